// Round 11
// baseline (491.568 us; speedup 1.0000x reference)
//
#include <hip/hip_runtime.h>
#include <math.h>

#define NN 4096
#define STRIPS 32
#define SW 128                        // strip width (columns per workgroup)
#define RING_ROWS 256                 // power of 2: slot = row & 255
#define RINGB (RING_ROWS * SW * 4)    // 131072 B
#define BATCH 64
#define NBATCH 65                     // (NN + 64) / BATCH
#define PAD 64                        // colbuf per-strip padding rows
#define COLPITCH (NN + 2 * PAD)
#define INFV 1e30f
#define SENTU 0xFFFFFFFFu             // memset(0xFF) sentinel, never a DP result

// lane l <- lane l-1 (whole-wave shift right by 1), VALU-latency cross-lane move
__device__ __forceinline__ float dpp_wave_shr1(float x) {
    return __int_as_float(__builtin_amdgcn_update_dpp(
        0, __float_as_int(x), 0x138 /*WAVE_SHR1*/, 0xf, 0xf, false));
}

// all 64 lanes load one boundary row each (clamped): always exactly 1 vmem inst
__device__ __forceinline__ float bload(const unsigned* colL, int row) {
    const int rowc = (row < NN) ? row : (NN - 1);
    unsigned u = __hip_atomic_load(colL + rowc, __ATOMIC_RELAXED,
                                   __HIP_MEMORY_SCOPE_AGENT);
    return __uint_as_float(u);
}

// rows [rb, rb+64) still hold the memset sentinel? (rows >= NN masked off)
__device__ __forceinline__ bool has_sent(float b, int rb, int lane) {
    return __any(((rb + lane) < NN) && (__float_as_uint(b) == SENTU));
}

// async-stage rows [rb, rb+64) (128 cols) into the LDS ring at slot (row&255).
// ALWAYS exactly 32 global_load_lds (source rows clamped to NN-2; slot from
// the UNCLAMPED row -- aliases only rows outside the live window).
__device__ __forceinline__ void stageB(const float* Sg, float* ring, int rb,
                                       int lane) {
    #pragma unroll
    for (int k = 0; k < 32; ++k) {
        const int r0 = rb + 2 * k;
        const int r0c = (r0 < NN - 1) ? r0 : (NN - 2);
        const int slot = r0 & (RING_ROWS - 1);
        const float* gsrc =
            Sg + (size_t)(r0c + (lane >> 5)) * NN + ((lane & 31) << 2);
        __builtin_amdgcn_global_load_lds(
            (const __attribute__((address_space(1))) unsigned*)gsrc,
            (__attribute__((address_space(3))) unsigned*)((char*)ring +
                                                         slot * (SW * 4)),
            16, 0, 0);
    }
}

// ---------------------------------------------------------------------------
// Producer/consumer DP: 32 workgroups x 2 waves, BATCH=64.
// Strip g owns cols [128g, 128g+128); compute lane l owns cols 2l, 2l+1; at
// step t lane l computes row r = t - l. Left/diag deps via DPP wave_shr1.
//
// Compute wave: per batch n: 64 ds_reads of this batch's rows (staged >= 2
//   batches ago); 64-step register chain with lane63's c1 going to an LDS
//   outbox (zero-divergence obp walk); lgkmcnt(0); ALL lanes read
//   outbox[lane] and fire ONE agent store each (publish rows [tb-63, tb]);
//   barrier. Publishing at compute-batch end cuts the inter-strip lag to 2.
// Support wave: per batch n: validate boundary rows [tb+64, tb+128)
//   (prefetched last batch; spin drains vmcnt but runs BEFORE stage issue so
//   the counted guard stays exact) -> inbox[(n+1)&1]; prefetch qv rows
//   [tb+128, tb+192); stage E rows [tb+128, tb+192) (compute batch n+2);
//   counted vmcnt(33|32) proves batch n-1's stage landed; barrier.
// Ring window: [tb-63, tb+128) live + [tb+128, tb+192) staging = 255-row
// span < 256 ring rows. Lag floor: T_g(m) >= T_{g-1}(m+2) => periods =
// NBATCH + 31*2 ~= 127 (vs 285 at BATCH=32) -- amortizes the measured
// ~3000cy fixed per-batch cost.
// ---------------------------------------------------------------------------
template <int DOEXP>
__global__ __launch_bounds__(128, 1) void dtw_dp(const float* __restrict__ S,
                                                 float* __restrict__ cost_out,
                                                 unsigned* __restrict__ colbuf) {
    __shared__ float ring[RING_ROWS * SW];   // 128 KB
    __shared__ float inbox[2][BATCH];
    __shared__ float outbox[BATCH];
    __shared__ float outdummy[64];

    const int tid = threadIdx.x;
    const int lane = tid & 63;
    const int b = blockIdx.x;
    const int g = ((b & 7) << 2) | (b >> 3);   // XCD-affinity strip remap

    const float* Sg = S + g * SW;
    const unsigned* colL = colbuf + (size_t)(g - 1) * COLPITCH + PAD;
    unsigned* colM = colbuf + (size_t)g * COLPITCH + PAD;

    if (tid < 64) {
        // ================= compute wave =================
        // clear pre-start ring slots [192,256): rows r<0 read 0 (INF+0=INF)
        {
            const float4 z = make_float4(0.f, 0.f, 0.f, 0.f);
            float4* r4 = reinterpret_cast<float4*>(&ring[192 * SW]);
            #pragma unroll
            for (int i = 0; i < 32; ++i) r4[i * 64 + lane] = z;
        }
        asm volatile("s_waitcnt lgkmcnt(0)" ::: "memory");
        __builtin_amdgcn_s_barrier();   // prologue barrier

        const bool lane0 = (lane == 0);
        const int ostep = (lane == 63) ? 1 : 0;
        float cur0 = INFV, cur1 = INFV;   // my c[r-1][2l], c[r-1][2l+1]
        float l1s = INFV, l2s = INFV;     // lane l-1's c1 from t-1, t-2
        float bprevc = INFV;              // boundary carry (row tb-1)
        float save = 0.f;

        // per-lane ring byte address of (row tb-lane, col 2*lane), batch 0
        unsigned caddr = ((unsigned)((0 - lane) & (RING_ROWS - 1)) << 9) |
                         ((unsigned)lane << 3);

        for (int n = 0; n < NBATCH; ++n) {
            const int tb = n << 6;
            const float binb = inbox[n & 1][lane];

            // this batch's 64 LDS reads (rows staged >= 2 batches ago);
            // compiler interleaves issue with the chain + fine lgkm waits
            float2 rv[BATCH];
            #pragma unroll
            for (int s = 0; s < BATCH; ++s)
                rv[s] = *reinterpret_cast<const float2*>(
                    (const char*)ring +
                    ((caddr + (unsigned)(s * 512)) & (RINGB - 1)));

            float* obp = (lane == 63) ? &outbox[0] : &outdummy[lane];
            float pbc = INFV;
            #pragma unroll
            for (int s = 0; s < BATCH; ++s) {
                float e0, e1;
                if (DOEXP) { e0 = __expf(-rv[s].x); e1 = __expf(-rv[s].y); }
                else       { e0 = rv[s].x;          e1 = rv[s].y; }
                float bcur;
                if (g == 0)
                    bcur = (n == 0 && s == 0) ? 0.f : INFV;   // (0,0) corner
                else
                    bcur = __int_as_float(
                        __builtin_amdgcn_readlane(__float_as_int(binb), s));
                const float bpv =
                    (g == 0) ? INFV : ((s == 0) ? bprevc : pbc);
                // chain: cndmask -> min3 -> add -> fmin -> add -> dpp
                const float L1 = lane0 ? bcur : l1s;   // c[r][col-1]
                const float L2 = lane0 ? bpv : l2s;    // c[r-1][col-1]
                const float m0 = fminf(fminf(L1, cur0), L2);
                const float c0 = e0 + m0;
                const float c1 = e1 + fminf(c0, fminf(cur0, cur1));
                *obp = c1;                 // lane63 -> outbox[s], rest -> dummy
                obp += ostep;
                const float sh = dpp_wave_shr1(c1);
                l2s = l1s; l1s = sh;
                cur0 = c0; cur1 = c1;
                pbc = bcur;
                if (s == 62) save = c1;    // final cell: n=64, s=62 (r=4095)
            }
            bprevc = pbc;
            caddr = (caddr + (unsigned)(BATCH * 512)) & (RINGB - 1);

            // publish rows [tb-63, tb]: outbox -> one agent store per lane
            asm volatile("s_waitcnt lgkmcnt(0)" ::: "memory");
            {
                const float ob = outbox[lane];
                asm volatile("s_waitcnt lgkmcnt(0)" ::: "memory");
                __hip_atomic_store(colM + (tb - 63 + lane),
                                   __float_as_uint(ob), __ATOMIC_RELAXED,
                                   __HIP_MEMORY_SCOPE_AGENT);
            }
            __builtin_amdgcn_s_barrier();
        }

        if (g == STRIPS - 1 && lane == 63) cost_out[0] = save;
    } else {
        // ================= support wave =================
        stageB(Sg, ring, 0, lane);     // rows [0,64)   (compute batch 0)
        stageB(Sg, ring, 64, lane);    // rows [64,128) (compute batch 1)
        float qv = INFV;
        if (g > 0) {
            qv = bload(colL, lane);
            while (has_sent(qv, 0, lane)) qv = bload(colL, lane);
            inbox[0][lane] = qv;
            qv = bload(colL, 64 + lane);           // rows [64,128)
        }
        asm volatile("s_waitcnt vmcnt(0) lgkmcnt(0)" ::: "memory");
        __builtin_amdgcn_s_barrier();   // prologue barrier

        for (int n = 0; n < NBATCH; ++n) {
            const int tb = n << 6;
            if (g > 0) {
                // validate rows [tb+64, tb+128) (compute batch n+1's inbox).
                // Spin (if any) drains vmcnt BEFORE the stage issue below,
                // so the counted guard stays correct on spin batches.
                const int vb = tb + 64;
                while (has_sent(qv, vb, lane)) qv = bload(colL, vb + lane);
                inbox[(n + 1) & 1][lane] = qv;
                qv = bload(colL, tb + 128 + lane);   // prefetch next validate
            }
            stageB(Sg, ring, tb + 128, lane);   // rows for compute batch n+2
            __builtin_amdgcn_sched_barrier(0);
            // counted wait: newest 33 (32 for g=0) = THIS batch's qv+stage;
            // forces batch n-1's stage ([tb+64,tb+128)) complete.
            if (g > 0) asm volatile("s_waitcnt vmcnt(33)" ::: "memory");
            else       asm volatile("s_waitcnt vmcnt(32)" ::: "memory");
            __builtin_amdgcn_sched_barrier(0);
            asm volatile("s_waitcnt lgkmcnt(0)" ::: "memory");
            __builtin_amdgcn_s_barrier();
        }
    }
}

// ---------------------------------------------------------------------------
// Fused: E = exp(-D)  AND  acc_grad[i,j] = d[i+1,j+1]+d[i+1,j]+d[i,j+1]-d[i,j]
// with d = exp(-exp(-D)) (zero-padded bottom/right).
// ---------------------------------------------------------------------------
__global__ __launch_bounds__(256) void eg_kernel(const float* __restrict__ D,
                                                 float* __restrict__ E,
                                                 float* __restrict__ G) {
    const int idx = blockIdx.x * 256 + threadIdx.x;
    const int i = idx >> 10;
    const int j = (idx & 1023) << 2;
    if (i >= NN) return;

    const float* row0 = D + (size_t)i * NN + j;
    const bool hasR = (i + 1) < NN;
    const bool hasC = (j + 4) < NN;

    const float4 r0 = *reinterpret_cast<const float4*>(row0);
    float4 r1 = make_float4(0.f, 0.f, 0.f, 0.f);
    if (hasR) r1 = *reinterpret_cast<const float4*>(row0 + NN);
    const float s0 = hasC ? row0[4] : 0.f;
    const float s1 = (hasR && hasC) ? row0[NN + 4] : 0.f;

    const float ex0 = __expf(-r0.x), ex1 = __expf(-r0.y);
    const float ex2 = __expf(-r0.z), ex3 = __expf(-r0.w);
    *reinterpret_cast<float4*>(E + (size_t)i * NN + j) =
        make_float4(ex0, ex1, ex2, ex3);

    const float a0 = __expf(-ex0), a1 = __expf(-ex1);
    const float a2 = __expf(-ex2), a3 = __expf(-ex3);
    const float a4 = hasC ? __expf(-__expf(-s0)) : 0.f;
    const float b0 = hasR ? __expf(-__expf(-r1.x)) : 0.f;
    const float b1 = hasR ? __expf(-__expf(-r1.y)) : 0.f;
    const float b2 = hasR ? __expf(-__expf(-r1.z)) : 0.f;
    const float b3 = hasR ? __expf(-__expf(-r1.w)) : 0.f;
    const float b4 = (hasR && hasC) ? __expf(-__expf(-s1)) : 0.f;

    float* go = G + (size_t)i * NN + j;
    go[0] = b1 + b0 + a1 - a0;
    go[1] = b2 + b1 + a2 - a1;
    go[2] = b3 + b2 + a3 - a2;
    go[3] = b4 + b3 + a4 - a3;
}

// fallback grad (no-E path only)
__device__ __forceinline__ float dfun(float x) { return __expf(-__expf(-x)); }

__global__ __launch_bounds__(256) void dtw_grad_kernel(const float* __restrict__ D,
                                                       float* __restrict__ G) {
    const int idx = blockIdx.x * 256 + threadIdx.x;
    const int i = idx >> 10;
    const int j = (idx & 1023) << 2;
    if (i >= NN) return;

    const float* row0 = D + (size_t)i * NN + j;
    const bool hasR = (i + 1) < NN;
    const bool hasC = (j + 4) < NN;

    const float4 r0 = *reinterpret_cast<const float4*>(row0);
    float4 r1 = make_float4(0.f, 0.f, 0.f, 0.f);
    if (hasR) r1 = *reinterpret_cast<const float4*>(row0 + NN);
    const float s0 = hasC ? row0[4] : 0.f;
    const float s1 = (hasR && hasC) ? row0[NN + 4] : 0.f;

    const float a0 = dfun(r0.x), a1 = dfun(r0.y), a2 = dfun(r0.z), a3 = dfun(r0.w);
    const float a4 = hasC ? dfun(s0) : 0.f;
    const float b0 = hasR ? dfun(r1.x) : 0.f;
    const float b1 = hasR ? dfun(r1.y) : 0.f;
    const float b2 = hasR ? dfun(r1.z) : 0.f;
    const float b3 = hasR ? dfun(r1.w) : 0.f;
    const float b4 = (hasR && hasC) ? dfun(s1) : 0.f;

    float* go = G + (size_t)i * NN + j;
    go[0] = b1 + b0 + a1 - a0;
    go[1] = b2 + b1 + a2 - a1;
    go[2] = b3 + b2 + a3 - a2;
    go[3] = b4 + b3 + a4 - a3;
}

// ---------------------------------------------------------------------------
extern "C" void kernel_launch(void* const* d_in, const int* in_sizes, int n_in,
                              void* d_out, int out_size, void* d_ws, size_t ws_size,
                              hipStream_t stream) {
    (void)in_sizes; (void)n_in; (void)out_size;
    const float* D = (const float*)d_in[0];
    float* out = (float*)d_out;

    const size_t colbytes = (size_t)STRIPS * COLPITCH * sizeof(unsigned);
    const size_t ebytes = (size_t)NN * NN * sizeof(float);
    const int gblocks = (NN * (NN / 4)) / 256;

    if (ws_size >= ebytes + colbytes) {
        float* E = (float*)d_ws;
        unsigned* colbuf = (unsigned*)((char*)d_ws + ebytes);
        hipMemsetAsync(colbuf, 0xFF, colbytes, stream);
        eg_kernel<<<gblocks, 256, 0, stream>>>(D, E, out + 1);
        dtw_dp<0><<<STRIPS, 128, 0, stream>>>(E, out, colbuf);
    } else {
        unsigned* colbuf = (ws_size >= colbytes) ? (unsigned*)d_ws
                                                 : (unsigned*)(out + 1);
        hipMemsetAsync(colbuf, 0xFF, colbytes, stream);
        dtw_dp<1><<<STRIPS, 128, 0, stream>>>(D, out, colbuf);
        dtw_grad_kernel<<<gblocks, 256, 0, stream>>>(D, out + 1);
    }
}